// Round 1
// baseline (1198.948 us; speedup 1.0000x reference)
//
#include <hip/hip_runtime.h>
#include <hip/hip_bf16.h>

typedef __hip_bfloat16 bf16_t;

constexpr int N_  = 4;
constexpr int C_  = 512;
constexpr int H_  = 128;
constexpr int W_  = 128;
constexpr int HW_ = H_ * W_;     // 16384
constexpr int O144 = 144;        // stacked D/E GEMM output rows
constexpr int C3_ = 48;

// ---------------- workspace layout (bytes) ----------------
// peak region: [0,64M) dilX bf16 | [64M,128M) eroX bf16 | PD f32 | PE f32 | weights | tiny
constexpr size_t OFF_DIL  = 0;                         // bf16 N*C*HW*2 = 67,108,864
constexpr size_t OFF_ERO  = 67108864;                  // bf16 67,108,864
constexpr size_t OFF_PD   = 134217728;                 // f32 4*144*16384*4 = 37,748,736
constexpr size_t OFF_PE   = 171966464;                 // f32 37,748,736
constexpr size_t OFF_WD   = 209715200;                 // 144*512*4 = 294,912
constexpr size_t OFF_WE   = 210010112;                 // 294,912
constexpr size_t OFF_WQ   = 210305024;                 // 48*512*4 = 98,304
constexpr size_t OFF_BQ   = 210403328;                 // 256
constexpr size_t OFF_WSUM = 210403584;                 // 4*16*16*4 = 4096
constexpr size_t OFF_WSM  = 210407680;                 // 4096
// aliased over dilX/eroX region (dead after the two big GEMMs):
constexpr size_t OFF_DX1   = 0;
constexpr size_t OFF_DX31  = 4194304;
constexpr size_t OFF_DX51  = 8388608;
constexpr size_t OFF_EX1   = 12582912;
constexpr size_t OFF_EX31  = 16777216;
constexpr size_t OFF_EX51  = 20971520;
constexpr size_t OFF_DIFF  = 25165824;
constexpr size_t OFF_F     = 29360128;                 // 4*48*16384*4 = 12,582,912
constexpr size_t OFF_QKV   = 41943040;                 // 12,582,912
constexpr size_t OFF_AX    = 54525952;                 // 4,194,304
constexpr size_t OFF_WEDGE = 58720256;                 // 262,144

// ---------------- weight prep: stack striped-conv taps into GEMM matrices ----------------
// WD rows: [0,16)=w1 ; [16,64)=w31 tap t rows 16+16t+o ; [64,144)=w51 tap t rows 64+16t+o
__global__ void prep_weights(const float* __restrict__ Dw1, const float* __restrict__ Dw31,
                             const float* __restrict__ Dw51,
                             const float* __restrict__ Ew1, const float* __restrict__ Ew31,
                             const float* __restrict__ Ew51,
                             const float* __restrict__ qw, const float* __restrict__ kw,
                             const float* __restrict__ vw,
                             const float* __restrict__ qb, const float* __restrict__ kb,
                             const float* __restrict__ vb,
                             float* __restrict__ WD, float* __restrict__ WE,
                             float* __restrict__ WQ, float* __restrict__ BQ) {
  int idx = blockIdx.x * 256 + threadIdx.x;
  const int sz = O144 * C_;
  if (idx < sz) {
    int r = idx / C_, c = idx % C_;
    float v;
    if (r < 16)       v = Dw1[r * C_ + c];
    else if (r < 64)  { int t = (r - 16) >> 4, o = (r - 16) & 15; v = Dw31[(o * C_ + c) * 3 + t]; }
    else              { int t = (r - 64) >> 4, o = (r - 64) & 15; v = Dw51[(o * C_ + c) * 5 + t]; }
    WD[idx] = v;
    if (r < 16)       v = Ew1[r * C_ + c];
    else if (r < 64)  { int t = (r - 16) >> 4, o = (r - 16) & 15; v = Ew31[(o * C_ + c) * 3 + t]; }
    else              { int t = (r - 64) >> 4, o = (r - 64) & 15; v = Ew51[(o * C_ + c) * 5 + t]; }
    WE[idx] = v;
  } else if (idx < sz + C3_ * C_) {
    int k = idx - sz;
    int r = k / C_, c = k % C_;
    const float* w = (r < 16) ? qw : (r < 32) ? kw : vw;
    WQ[k] = w[(r & 15) * C_ + c];
  } else if (idx < sz + C3_ * C_ + C3_) {
    int r = idx - sz - C3_ * C_;
    const float* bb = (r < 16) ? qb : (r < 32) ? kb : vb;
    BQ[r] = bb[r & 15];
  }
}

// ---------------- dilate (3x3 max) + erode (3x3 min), borders neutral ----------------
__global__ void dilero(const float* __restrict__ dxin, bf16_t* __restrict__ dil,
                       bf16_t* __restrict__ ero) {
  int idx = blockIdx.x * 256 + threadIdx.x;       // < N*C*HW = 33,554,432
  int pix = idx & (HW_ - 1);
  int plane = idx >> 14;                          // b*C + c
  int y = pix >> 7, x = pix & 127;
  const float* p = dxin + ((size_t)plane << 14);
  float mx = -INFINITY, mn = INFINITY;
  #pragma unroll
  for (int dy = -1; dy <= 1; ++dy) {
    int yy = y + dy; if (yy < 0 || yy >= H_) continue;
    #pragma unroll
    for (int dxx = -1; dxx <= 1; ++dxx) {
      int xx = x + dxx; if (xx < 0 || xx >= W_) continue;
      float v = p[yy * W_ + xx];
      mx = fmaxf(mx, v); mn = fminf(mn, v);
    }
  }
  dil[idx] = __float2bfloat16(mx);
  ero[idx] = __float2bfloat16(mn);
}

// ---------------- generic 1x1-conv GEMM: Out[b][O][p] = W[O][512] @ X[b][512][p] ----------------
__device__ __forceinline__ void loadX8(const float* __restrict__ s, float* t) {
  float4 a = *(const float4*)s; float4 b = *(const float4*)(s + 4);
  t[0]=a.x; t[1]=a.y; t[2]=a.z; t[3]=a.w; t[4]=b.x; t[5]=b.y; t[6]=b.z; t[7]=b.w;
}
__device__ __forceinline__ void loadX8(const bf16_t* __restrict__ s, float* t) {
  uint4 u = *(const uint4*)s;
  t[0]=__uint_as_float(u.x << 16); t[1]=__uint_as_float(u.x & 0xffff0000u);
  t[2]=__uint_as_float(u.y << 16); t[3]=__uint_as_float(u.y & 0xffff0000u);
  t[4]=__uint_as_float(u.z << 16); t[5]=__uint_as_float(u.z & 0xffff0000u);
  t[6]=__uint_as_float(u.w << 16); t[7]=__uint_as_float(u.w & 0xffff0000u);
}

template <typename XT>
__global__ __launch_bounds__(256) void gemm48(const XT* __restrict__ X,
                                              const float* __restrict__ Wm,
                                              const float* __restrict__ bias,
                                              float* __restrict__ Out) {
  // grid: (HW/128, O/48, N); block 256. Per-thread 6o x 4p accumulators.
  int b  = blockIdx.z;
  int o0 = blockIdx.y * 48;
  int p0 = blockIdx.x * 128;
  int Otot = gridDim.y * 48;
  __shared__ __align__(16) float Xs[16][128];
  __shared__ __align__(16) float Ws[16][8][8];   // [kk][o-group][slot<6]
  int tid = threadIdx.x;
  int pg  = tid & 31;     // pixel group -> px = pg*4
  int og  = tid >> 5;     // o group -> o = og*6..og*6+5
  float acc[6][4] = {};
  const XT* Xb = X + (size_t)b * C_ * HW_;
  for (int k0 = 0; k0 < C_; k0 += 16) {
    {
      int e = tid * 8;
      int kk = e >> 7, px = e & 127;
      float tmp[8];
      loadX8(Xb + (size_t)(k0 + kk) * HW_ + p0 + px, tmp);
      #pragma unroll
      for (int i = 0; i < 8; ++i) Xs[kk][px + i] = tmp[i];
    }
    #pragma unroll
    for (int i = 0; i < 3; ++i) {
      int e = tid * 3 + i;            // 0..767 covers 48x16
      int oo = e >> 4, kk = e & 15;
      Ws[kk][oo / 6][oo % 6] = Wm[(size_t)(o0 + oo) * C_ + k0 + kk];
    }
    __syncthreads();
    #pragma unroll
    for (int kk = 0; kk < 16; ++kk) {
      float4 xv = *(const float4*)&Xs[kk][pg * 4];
      float4 wa = *(const float4*)&Ws[kk][og][0];
      float2 wb = *(const float2*)&Ws[kk][og][4];
      float wv[6] = {wa.x, wa.y, wa.z, wa.w, wb.x, wb.y};
      float xs[4] = {xv.x, xv.y, xv.z, xv.w};
      #pragma unroll
      for (int o = 0; o < 6; ++o)
        #pragma unroll
        for (int p = 0; p < 4; ++p) acc[o][p] += wv[o] * xs[p];
    }
    __syncthreads();
  }
  #pragma unroll
  for (int o = 0; o < 6; ++o) {
    int oc = o0 + og * 6 + o;
    float bi = bias ? bias[oc] : 0.f;
    float4 r;
    r.x = acc[o][0] + bi; r.y = acc[o][1] + bi; r.z = acc[o][2] + bi; r.w = acc[o][3] + bi;
    *(float4*)&Out[((size_t)b * Otot + oc) * HW_ + p0 + pg * 4] = r;
  }
}

// ---------------- tap-combine: PD/PE rows -> Dx1/Dx31/Dx51/Ex1/Ex31/Ex51 + difference ----------------
__global__ void combine(const float* __restrict__ PD, const float* __restrict__ PE,
                        const float* __restrict__ Db1, const float* __restrict__ Db31,
                        const float* __restrict__ Db51,
                        const float* __restrict__ Eb1, const float* __restrict__ Eb31,
                        const float* __restrict__ Eb51,
                        float* __restrict__ Dx1, float* __restrict__ Dx31, float* __restrict__ Dx51,
                        float* __restrict__ Ex1, float* __restrict__ Ex31, float* __restrict__ Ex51,
                        float* __restrict__ Diff) {
  int idx = blockIdx.x * 256 + threadIdx.x;   // b*16*HW
  int pix = idx & (HW_ - 1);
  int o = (idx >> 14) & 15;
  int b = idx >> 18;
  int y = pix >> 7;
  const float* pd = PD + (size_t)b * O144 * HW_;
  const float* pe = PE + (size_t)b * O144 * HW_;
  float d1 = pd[o * HW_ + pix] + Db1[o];
  float e1 = pe[o * HW_ + pix] + Eb1[o];
  float d31 = Db31[o], e31 = Eb31[o];
  #pragma unroll
  for (int t = 0; t < 3; ++t) {
    int yy = y - 1 + t;
    if (yy >= 0 && yy < H_) {
      int pp = pix + (t - 1) * W_;
      d31 += pd[(16 + t * 16 + o) * HW_ + pp];
      e31 += pe[(16 + t * 16 + o) * HW_ + pp];
    }
  }
  float d51 = Db51[o], e51 = Eb51[o];
  #pragma unroll
  for (int t = 0; t < 5; ++t) {
    int yy = y - 2 + t;
    if (yy >= 0 && yy < H_) {
      int pp = pix + (t - 2) * W_;
      d51 += pd[(64 + t * 16 + o) * HW_ + pp];
      e51 += pe[(64 + t * 16 + o) * HW_ + pp];
    }
  }
  Dx1[idx] = d1;  Ex1[idx] = e1;
  Dx31[idx] = d31; Ex31[idx] = e31;
  Dx51[idx] = d51; Ex51[idx] = e51;
  Diff[idx] = 2.f * d1 + d31 + d51 - 2.f * e1 - e31 - e51;
}

// ---------------- horizontal 1x3/1x5 convs + BN + relu -> F = dilF - eroF [b,48,HW] ----------------
__global__ void fkern(const float* __restrict__ Dx1, const float* __restrict__ Dx31,
                      const float* __restrict__ Dx51,
                      const float* __restrict__ Ex1, const float* __restrict__ Ex31,
                      const float* __restrict__ Ex51,
                      const float* __restrict__ Dw13, const float* __restrict__ Db13,
                      const float* __restrict__ Dw15, const float* __restrict__ Db15,
                      const float* __restrict__ Ew13, const float* __restrict__ Eb13,
                      const float* __restrict__ Ew15, const float* __restrict__ Eb15,
                      const float* __restrict__ Dg, const float* __restrict__ Dbe,
                      const float* __restrict__ Dm, const float* __restrict__ Dv,
                      const float* __restrict__ Eg, const float* __restrict__ Ebe,
                      const float* __restrict__ Em, const float* __restrict__ Ev,
                      float* __restrict__ F) {
  int idx = blockIdx.x * 256 + threadIdx.x;   // b*48*HW
  int pix = idx & (HW_ - 1);
  int ch = (idx >> 14) % 48;
  int b = (idx >> 14) / 48;
  int x = pix & 127;
  float dval, eval;
  if (ch < 16) {
    int o = ch;
    dval = Dx1[((b * 16 + o) << 14) + pix];
    eval = Ex1[((b * 16 + o) << 14) + pix];
  } else if (ch < 32) {
    int o = ch - 16;
    float da = Db13[o], ea = Eb13[o];
    for (int m = 0; m < 16; ++m) {
      const float* drow = Dx31 + ((b * 16 + m) << 14) + pix;
      const float* erow = Ex31 + ((b * 16 + m) << 14) + pix;
      #pragma unroll
      for (int t = 0; t < 3; ++t) {
        int xx = x - 1 + t;
        if (xx < 0 || xx >= W_) continue;
        da += Dw13[(o * 16 + m) * 3 + t] * drow[t - 1];
        ea += Ew13[(o * 16 + m) * 3 + t] * erow[t - 1];
      }
    }
    dval = da; eval = ea;
  } else {
    int o = ch - 32;
    float da = Db15[o], ea = Eb15[o];
    for (int m = 0; m < 16; ++m) {
      const float* drow = Dx51 + ((b * 16 + m) << 14) + pix;
      const float* erow = Ex51 + ((b * 16 + m) << 14) + pix;
      #pragma unroll
      for (int t = 0; t < 5; ++t) {
        int xx = x - 2 + t;
        if (xx < 0 || xx >= W_) continue;
        da += Dw15[(o * 16 + m) * 5 + t] * drow[t - 2];
        ea += Ew15[(o * 16 + m) * 5 + t] * erow[t - 2];
      }
    }
    dval = da; eval = ea;
  }
  float sD = Dg[ch] * rsqrtf(Dv[ch] + 1e-5f);
  float fD = fmaxf((dval - Dm[ch]) * sD + Dbe[ch], 0.f);
  float sE = Eg[ch] * rsqrtf(Ev[ch] + 1e-5f);
  float fE = fmaxf((eval - Em[ch]) * sE + Ebe[ch], 0.f);
  F[idx] = fD - fE;
}

// ---------------- depthwise 3x3 + pointwise 48->16 + relu + mean/max + sigmoid -> Wedge ----------------
__global__ void edgewedge(const float* __restrict__ F, const float* __restrict__ dww,
                          const float* __restrict__ dwb, const float* __restrict__ pww,
                          const float* __restrict__ pwb, const float* __restrict__ cw,
                          const float* __restrict__ cb, float* __restrict__ Wedge) {
  int idx = blockIdx.x * 256 + threadIdx.x;   // b*HW
  int pix = idx & (HW_ - 1);
  int b = idx >> 14;
  int y = pix >> 7, x = pix & 127;
  float dwo[48];
  const float* Fb = F + ((size_t)b * 48 << 14);
  for (int g = 0; g < 48; ++g) {
    float a = dwb[g];
    #pragma unroll
    for (int dy = 0; dy < 3; ++dy) {
      int yy = y - 1 + dy; if (yy < 0 || yy >= H_) continue;
      #pragma unroll
      for (int dxx = 0; dxx < 3; ++dxx) {
        int xx = x - 1 + dxx; if (xx < 0 || xx >= W_) continue;
        a += dww[g * 9 + dy * 3 + dxx] * Fb[(g << 14) + yy * W_ + xx];
      }
    }
    dwo[g] = a;
  }
  float sum = 0.f, mx = -INFINITY;
  for (int o = 0; o < 16; ++o) {
    float e = pwb[o];
    for (int g = 0; g < 48; ++g) e += pww[o * 48 + g] * dwo[g];
    e = fmaxf(e, 0.f);
    sum += e; mx = fmaxf(mx, e);
  }
  float z = cw[0] * (sum * (1.f / 16.f)) + cw[1] * mx + cb[0];
  Wedge[idx] = 1.f / (1.f + expf(-z));
}

// ---------------- attention: weight+gate accumulation (Q@K + Q@diff, reshape semantics) ----------------
__global__ void attn_qk(const float* __restrict__ QKV, const float* __restrict__ Diff,
                        float* __restrict__ wsum) {
  int b = blockIdx.y;
  int i = threadIdx.x >> 4, j = threadIdx.x & 15;
  const float* Q  = QKV + (size_t)b * C3_ * HW_;    // rows 0..15
  const float* Kf = Q + 16 * HW_;                   // rows 16..31 flat
  const float* Df = Diff + (size_t)b * 16 * HW_;
  __shared__ float Qs[16][512];
  __shared__ float KD[512][16];
  float acc = 0.f;
  int p0 = blockIdx.x * 2048;
  for (int c0 = p0; c0 < p0 + 2048; c0 += 512) {
    for (int e = threadIdx.x; e < 16 * 512; e += 256) {
      int r = e >> 9, p = e & 511;
      Qs[r][p] = Q[(r << 14) + c0 + p];
    }
    for (int e = threadIdx.x; e < 512 * 16; e += 256) {
      int f = (c0 << 4) + e;                        // flat f = p*16 + j
      KD[e >> 4][e & 15] = Kf[f] + Df[f];
    }
    __syncthreads();
    for (int p = 0; p < 512; ++p) acc += Qs[i][p] * KD[p][j];
    __syncthreads();
  }
  atomicAdd(&wsum[(b << 8) + threadIdx.x], acc);
}

// softmax over axis=1 (rows i) for each column j
__global__ void softmaxk(const float* __restrict__ wsum, float* __restrict__ wsm) {
  int b = blockIdx.x;
  __shared__ float s[16][16];
  __shared__ float colmx[16], colsum[16];
  int i = threadIdx.x >> 4, j = threadIdx.x & 15;
  s[i][j] = wsum[(b << 8) + threadIdx.x];
  __syncthreads();
  if (threadIdx.x < 16) {
    int jj = threadIdx.x;
    float mx = -INFINITY;
    for (int ii = 0; ii < 16; ++ii) mx = fmaxf(mx, s[ii][jj]);
    float sm = 0.f;
    for (int ii = 0; ii < 16; ++ii) sm += expf(s[ii][jj] - mx);
    colmx[jj] = mx; colsum[jj] = sm;
  }
  __syncthreads();
  wsm[(b << 8) + threadIdx.x] = expf(s[i][j] - colmx[j]) / colsum[j];
}

// attenX[b][m][pix] = (1+Wedge[q]) * sum_s wsm[pix&15][s] * V[s][q],  q = m*1024 + (pix>>4)
__global__ void attenx_k(const float* __restrict__ QKV, const float* __restrict__ wsm,
                         const float* __restrict__ Wedge, float* __restrict__ AX) {
  int idx = blockIdx.x * 256 + threadIdx.x;   // b*16*HW
  int pix = idx & (HW_ - 1);
  int m = (idx >> 14) & 15;
  int b = idx >> 18;
  __shared__ float ws[256];
  ws[threadIdx.x] = wsm[(b << 8) + threadIdx.x];
  __syncthreads();
  int q = (m << 10) + (pix >> 4);
  int r = pix & 15;
  const float* V = QKV + (size_t)b * C3_ * HW_ + (size_t)32 * HW_;
  float a = 0.f;
  #pragma unroll
  for (int s = 0; s < 16; ++s) a += ws[(r << 4) + s] * V[(s << 14) + q];
  AX[idx] = a * (1.f + Wedge[(b << 14) + q]);
}

// out[b][oc][pix] = sum_m rw[oc][m]*attenX[b][m][pix] + rb[oc] + dx[b][oc][pix]
__global__ __launch_bounds__(256) void finalconv(const float* __restrict__ AX,
                                                 const float* __restrict__ rw,
                                                 const float* __restrict__ rb,
                                                 const float* __restrict__ dxin,
                                                 float* __restrict__ out) {
  int blk = blockIdx.x;            // N*HW/256 = 256 blocks
  int b = blk >> 6;
  int p0 = (blk & 63) << 8;
  __shared__ float ax[16][256];
  for (int e = threadIdx.x; e < 16 * 256; e += 256) {
    int m = e >> 8, p = e & 255;
    ax[m][p] = AX[((size_t)(b * 16 + m) << 14) + p0 + p];
  }
  __syncthreads();
  int p = threadIdx.x;
  for (int oc = 0; oc < 512; ++oc) {
    float a = rb[oc];
    #pragma unroll
    for (int m = 0; m < 16; ++m) a += rw[oc * 16 + m] * ax[m][p];
    size_t oi = ((size_t)(b * C_ + oc) << 14) + p0 + p;
    out[oi] = a + dxin[oi];
  }
}

extern "C" void kernel_launch(void* const* d_in, const int* in_sizes, int n_in,
                              void* d_out, int out_size, void* d_ws, size_t ws_size,
                              hipStream_t stream) {
  (void)in_sizes; (void)n_in; (void)out_size; (void)ws_size;
  const float* ex   = (const float*)d_in[0];
  const float* dx   = (const float*)d_in[1];
  const float* Dw1  = (const float*)d_in[2];
  const float* Db1  = (const float*)d_in[3];
  const float* Dw31 = (const float*)d_in[4];
  const float* Db31 = (const float*)d_in[5];
  const float* Dw13 = (const float*)d_in[6];
  const float* Db13 = (const float*)d_in[7];
  const float* Dw51 = (const float*)d_in[8];
  const float* Db51 = (const float*)d_in[9];
  const float* Dw15 = (const float*)d_in[10];
  const float* Db15 = (const float*)d_in[11];
  const float* Dg   = (const float*)d_in[12];
  const float* Dbe  = (const float*)d_in[13];
  const float* Dm   = (const float*)d_in[14];
  const float* Dv   = (const float*)d_in[15];
  const float* Ew1  = (const float*)d_in[16];
  const float* Eb1  = (const float*)d_in[17];
  const float* Ew31 = (const float*)d_in[18];
  const float* Eb31 = (const float*)d_in[19];
  const float* Ew13 = (const float*)d_in[20];
  const float* Eb13 = (const float*)d_in[21];
  const float* Ew51 = (const float*)d_in[22];
  const float* Eb51 = (const float*)d_in[23];
  const float* Ew15 = (const float*)d_in[24];
  const float* Eb15 = (const float*)d_in[25];
  const float* Eg   = (const float*)d_in[26];
  const float* Ebe  = (const float*)d_in[27];
  const float* Em   = (const float*)d_in[28];
  const float* Ev   = (const float*)d_in[29];
  const float* dww  = (const float*)d_in[30];
  const float* dwb  = (const float*)d_in[31];
  const float* pww  = (const float*)d_in[32];
  const float* pwb  = (const float*)d_in[33];
  const float* qw   = (const float*)d_in[34];
  const float* qb   = (const float*)d_in[35];
  const float* kw   = (const float*)d_in[36];
  const float* kb   = (const float*)d_in[37];
  const float* vw   = (const float*)d_in[38];
  const float* vb   = (const float*)d_in[39];
  const float* rw   = (const float*)d_in[40];
  const float* rb   = (const float*)d_in[41];
  const float* cw   = (const float*)d_in[42];
  const float* cb   = (const float*)d_in[43];

  char* ws = (char*)d_ws;
  bf16_t* DIL = (bf16_t*)(ws + OFF_DIL);
  bf16_t* ERO = (bf16_t*)(ws + OFF_ERO);
  float* PD   = (float*)(ws + OFF_PD);
  float* PE   = (float*)(ws + OFF_PE);
  float* WD   = (float*)(ws + OFF_WD);
  float* WE   = (float*)(ws + OFF_WE);
  float* WQ   = (float*)(ws + OFF_WQ);
  float* BQ   = (float*)(ws + OFF_BQ);
  float* WSUM = (float*)(ws + OFF_WSUM);
  float* WSM  = (float*)(ws + OFF_WSM);
  float* DX1  = (float*)(ws + OFF_DX1);
  float* DX31 = (float*)(ws + OFF_DX31);
  float* DX51 = (float*)(ws + OFF_DX51);
  float* EX1  = (float*)(ws + OFF_EX1);
  float* EX31 = (float*)(ws + OFF_EX31);
  float* EX51 = (float*)(ws + OFF_EX51);
  float* DIFF = (float*)(ws + OFF_DIFF);
  float* Fb   = (float*)(ws + OFF_F);
  float* QKV  = (float*)(ws + OFF_QKV);
  float* AX   = (float*)(ws + OFF_AX);
  float* WEDG = (float*)(ws + OFF_WEDGE);

  prep_weights<<<385, 256, 0, stream>>>(Dw1, Dw31, Dw51, Ew1, Ew31, Ew51,
                                        qw, kw, vw, qb, kb, vb, WD, WE, WQ, BQ);
  dilero<<<(N_ * C_ * HW_) / 256, 256, 0, stream>>>(dx, DIL, ERO);
  gemm48<bf16_t><<<dim3(HW_ / 128, 3, N_), 256, 0, stream>>>(DIL, WD, nullptr, PD);
  gemm48<bf16_t><<<dim3(HW_ / 128, 3, N_), 256, 0, stream>>>(ERO, WE, nullptr, PE);
  combine<<<(N_ * 16 * HW_) / 256, 256, 0, stream>>>(PD, PE, Db1, Db31, Db51, Eb1, Eb31, Eb51,
                                                     DX1, DX31, DX51, EX1, EX31, EX51, DIFF);
  gemm48<float><<<dim3(HW_ / 128, 1, N_), 256, 0, stream>>>(ex, WQ, BQ, QKV);
  fkern<<<(N_ * 48 * HW_) / 256, 256, 0, stream>>>(DX1, DX31, DX51, EX1, EX31, EX51,
                                                   Dw13, Db13, Dw15, Db15, Ew13, Eb13, Ew15, Eb15,
                                                   Dg, Dbe, Dm, Dv, Eg, Ebe, Em, Ev, Fb);
  edgewedge<<<(N_ * HW_) / 256, 256, 0, stream>>>(Fb, dww, dwb, pww, pwb, cw, cb, WEDG);
  hipMemsetAsync(ws + OFF_WSUM, 0, 4096, stream);
  attn_qk<<<dim3(8, N_), 256, 0, stream>>>(QKV, DIFF, WSUM);
  softmaxk<<<N_, 256, 0, stream>>>(WSUM, WSM);
  attenx_k<<<(N_ * 16 * HW_) / 256, 256, 0, stream>>>(QKV, WSM, WEDG, AX);
  finalconv<<<(N_ * HW_) / 256, 256, 0, stream>>>(AX, rw, rb, dx, (float*)d_out);
}

// Round 2
// 919.737 us; speedup vs baseline: 1.3036x; 1.3036x over previous
//
#include <hip/hip_runtime.h>
#include <hip/hip_bf16.h>

typedef __hip_bfloat16 bf16_t;
typedef __attribute__((ext_vector_type(8))) short short8;   // bf16x8 MFMA frag
typedef __attribute__((ext_vector_type(4))) float floatx4;  // f32x4 acc frag

constexpr int N_  = 4;
constexpr int C_  = 512;
constexpr int H_  = 128;
constexpr int W_  = 128;
constexpr int HW_ = H_ * W_;     // 16384
constexpr int O144 = 144;        // stacked D/E GEMM output rows
constexpr int C3_ = 48;

// ---------------- workspace layout (bytes) ----------------
constexpr size_t OFF_DILT = 0;                         // bf16 [4][16384][512] = 67,108,864
constexpr size_t OFF_EROT = 67108864;                  // bf16 67,108,864
constexpr size_t OFF_PD   = 134217728;                 // f32 4*144*16384*4 = 37,748,736
constexpr size_t OFF_PE   = 171966464;                 // f32 37,748,736
constexpr size_t OFF_WD   = 209715200;                 // bf16 144*512*2 = 147,456
constexpr size_t OFF_WE   = 210010112;                 // bf16 147,456
constexpr size_t OFF_WQ   = 210305024;                 // f32 48*512*4 = 98,304
constexpr size_t OFF_BQ   = 210403328;                 // 256
constexpr size_t OFF_WSUM = 210403584;                 // 4096
constexpr size_t OFF_WSM  = 210407680;                 // 4096
// aliased over DILT region (dead after the two MFMA GEMMs):
constexpr size_t OFF_DX1   = 0;
constexpr size_t OFF_DX31  = 4194304;
constexpr size_t OFF_DX51  = 8388608;
constexpr size_t OFF_EX1   = 12582912;
constexpr size_t OFF_EX31  = 16777216;
constexpr size_t OFF_EX51  = 20971520;
constexpr size_t OFF_DIFF  = 25165824;
constexpr size_t OFF_F     = 29360128;                 // 12,582,912
constexpr size_t OFF_QKV   = 41943040;                 // 12,582,912
constexpr size_t OFF_AX    = 54525952;                 // 4,194,304
constexpr size_t OFF_WEDGE = 58720256;                 // 262,144
// aliased over EROT region (dead after GEMMs):
constexpr size_t OFF_E16   = 67108864;                 // f32 4*16*16384*4 = 4,194,304

// ---------------- weight prep: stack striped-conv taps; bf16 for MFMA ----------------
__global__ void prep_weights(const float* __restrict__ Dw1, const float* __restrict__ Dw31,
                             const float* __restrict__ Dw51,
                             const float* __restrict__ Ew1, const float* __restrict__ Ew31,
                             const float* __restrict__ Ew51,
                             const float* __restrict__ qw, const float* __restrict__ kw,
                             const float* __restrict__ vw,
                             const float* __restrict__ qb, const float* __restrict__ kb,
                             const float* __restrict__ vb,
                             bf16_t* __restrict__ WD, bf16_t* __restrict__ WE,
                             float* __restrict__ WQ, float* __restrict__ BQ) {
  int idx = blockIdx.x * 256 + threadIdx.x;
  const int sz = O144 * C_;
  if (idx < sz) {
    int r = idx / C_, c = idx % C_;
    float v;
    if (r < 16)       v = Dw1[r * C_ + c];
    else if (r < 64)  { int t = (r - 16) >> 4, o = (r - 16) & 15; v = Dw31[(o * C_ + c) * 3 + t]; }
    else              { int t = (r - 64) >> 4, o = (r - 64) & 15; v = Dw51[(o * C_ + c) * 5 + t]; }
    WD[idx] = __float2bfloat16(v);
    if (r < 16)       v = Ew1[r * C_ + c];
    else if (r < 64)  { int t = (r - 16) >> 4, o = (r - 16) & 15; v = Ew31[(o * C_ + c) * 3 + t]; }
    else              { int t = (r - 64) >> 4, o = (r - 64) & 15; v = Ew51[(o * C_ + c) * 5 + t]; }
    WE[idx] = __float2bfloat16(v);
  } else if (idx < sz + C3_ * C_) {
    int k = idx - sz;
    int r = k / C_, c = k % C_;
    const float* w = (r < 16) ? qw : (r < 32) ? kw : vw;
    WQ[k] = w[(r & 15) * C_ + c];
  } else if (idx < sz + C3_ * C_ + C3_) {
    int r = idx - sz - C3_ * C_;
    const float* bb = (r < 16) ? qb : (r < 32) ? kb : vb;
    BQ[r] = bb[r & 15];
  }
}

// ---------------- dilate+erode, 8 px/thread, writes TRANSPOSED bf16 [b][pix][c] ----------------
__device__ __forceinline__ void accrow(const float* __restrict__ rowp, int ax, int x0, int dx4,
                                       float* vmax, float* vmin) {
  float buf[16];
  *(float4*)&buf[0]  = *(const float4*)(rowp + ax);
  *(float4*)&buf[4]  = *(const float4*)(rowp + x0);
  *(float4*)&buf[8]  = *(const float4*)(rowp + x0 + 4);
  *(float4*)&buf[12] = *(const float4*)(rowp + dx4);
  #pragma unroll
  for (int j = 0; j < 10; ++j) {
    vmax[j] = fmaxf(vmax[j], buf[j + 3]);
    vmin[j] = fminf(vmin[j], buf[j + 3]);
  }
}

__global__ __launch_bounds__(256) void dilero_t(const float* __restrict__ dxin,
                                                bf16_t* __restrict__ dilT,
                                                bf16_t* __restrict__ eroT) {
  // grid: (32 cT, 128 y, 4 b); block 256: thread = (cl = t>>4, xg = t&15)
  int cT = blockIdx.x, y = blockIdx.y, b = blockIdx.z;
  int t = threadIdx.x;
  int cl = t >> 4;
  int xg = t & 15, x0 = xg * 8;
  int c = cT * 16 + cl;
  const float* p = dxin + ((size_t)(b * C_ + c)) * HW_;
  int ax  = (x0 == 0)   ? 0   : x0 - 4;
  int dx4 = (x0 == 120) ? 124 : x0 + 8;
  float vmax[10], vmin[10];
  #pragma unroll
  for (int j = 0; j < 10; ++j) { vmax[j] = -INFINITY; vmin[j] = INFINITY; }
  if (y > 0)   accrow(p + (y - 1) * W_, ax, x0, dx4, vmax, vmin);
  accrow(p + y * W_, ax, x0, dx4, vmax, vmin);
  if (y < 127) accrow(p + (y + 1) * W_, ax, x0, dx4, vmax, vmin);
  if (xg == 0)  { vmax[0] = -INFINITY; vmin[0] = INFINITY; }   // x=-1 excluded
  if (xg == 15) { vmax[9] = -INFINITY; vmin[9] = INFINITY; }   // x=128 excluded
  __shared__ bf16_t ds_d[128][18];   // rows of 18 bf16 (36B): conflict-light
  __shared__ bf16_t ds_e[128][18];
  #pragma unroll
  for (int i = 0; i < 8; ++i) {
    float mx = fmaxf(fmaxf(vmax[i], vmax[i + 1]), vmax[i + 2]);
    float mn = fminf(fminf(vmin[i], vmin[i + 1]), vmin[i + 2]);
    ds_d[x0 + i][cl] = __float2bfloat16(mx);
    ds_e[x0 + i][cl] = __float2bfloat16(mn);
  }
  __syncthreads();
  // write phase: t>>7 selects map, j = t&127 the pixel; 16 bf16 = 32B per pixel
  int j = t & 127;
  const uint* rp = (t >> 7) ? (const uint*)&ds_e[j][0] : (const uint*)&ds_d[j][0];
  uint v0 = rp[0], v1 = rp[1], v2 = rp[2], v3 = rp[3];
  uint v4 = rp[4], v5 = rp[5], v6 = rp[6], v7 = rp[7];
  bf16_t* dst = (t >> 7) ? eroT : dilT;
  size_t base = ((size_t)(b * HW_ + y * W_ + j)) * C_ + cT * 16;
  uint4* op = (uint4*)(dst + base);
  op[0] = make_uint4(v0, v1, v2, v3);
  op[1] = make_uint4(v4, v5, v6, v7);
}

// ---------------- MFMA GEMM: Out[b][144][HW] = W[144][512] @ Xt[b][HW][512]^T ----------------
__global__ __launch_bounds__(256) void gemm_mfma(const bf16_t* __restrict__ WDb,
                                                 const bf16_t* __restrict__ WEb,
                                                 const bf16_t* __restrict__ DILt,
                                                 const bf16_t* __restrict__ EROt,
                                                 float* __restrict__ PD,
                                                 float* __restrict__ PE) {
  // grid: (128 pT, 3 mT, 8 = b*2maps). Per block M=48,N=128,K=512.
  constexpr int LDA = 40;   // padded bf16 row stride (80B, 16B-aligned, 2-way banks)
  constexpr int LDB = 40;
  __shared__ bf16_t As[48 * LDA];
  __shared__ bf16_t Bs[128 * LDB];
  int z = blockIdx.z;
  int b = z & 3, map = z >> 2;
  const bf16_t* Wb = map ? WEb : WDb;
  const bf16_t* Xt = map ? EROt : DILt;
  float* Out = map ? PE : PD;
  int m0 = blockIdx.y * 48;
  int p0 = blockIdx.x * 128;
  int tid = threadIdx.x;
  int wave = tid >> 6, lane = tid & 63;
  int quad = lane >> 4, l16 = lane & 15;
  floatx4 acc[3][2] = {};
  const bf16_t* Xb = Xt + ((size_t)b * HW_ + p0) * C_;
  for (int k0 = 0; k0 < C_; k0 += 32) {
    if (tid < 192) {                       // A tile: 48 x 32
      int m = tid >> 2, q = tid & 3;
      uint4 v = *(const uint4*)(Wb + (size_t)(m0 + m) * C_ + k0 + q * 8);
      *(uint4*)(&As[m * LDA + q * 8]) = v;
    }
    #pragma unroll
    for (int s = 0; s < 2; ++s) {          // B tile: 128 x 32
      int slot = tid + s * 256;
      int pp = slot >> 2, q = slot & 3;
      uint4 v = *(const uint4*)(Xb + (size_t)pp * C_ + k0 + q * 8);
      *(uint4*)(&Bs[pp * LDB + q * 8]) = v;
    }
    __syncthreads();
    short8 bfr[2];
    #pragma unroll
    for (int nt = 0; nt < 2; ++nt)
      bfr[nt] = *(const short8*)(&Bs[(wave * 32 + nt * 16 + l16) * LDB + quad * 8]);
    #pragma unroll
    for (int mt = 0; mt < 3; ++mt) {
      short8 afr = *(const short8*)(&As[(mt * 16 + l16) * LDA + quad * 8]);
      #pragma unroll
      for (int nt = 0; nt < 2; ++nt)
        acc[mt][nt] = __builtin_amdgcn_mfma_f32_16x16x32_bf16(afr, bfr[nt], acc[mt][nt], 0, 0, 0);
    }
    __syncthreads();
  }
  // D layout: col(n) = lane&15, row(m) = quad*4 + reg
  #pragma unroll
  for (int mt = 0; mt < 3; ++mt)
    #pragma unroll
    for (int nt = 0; nt < 2; ++nt) {
      int n = p0 + wave * 32 + nt * 16 + l16;
      #pragma unroll
      for (int r = 0; r < 4; ++r) {
        int m = m0 + mt * 16 + quad * 4 + r;
        Out[((size_t)b * O144 + m) * HW_ + n] = acc[mt][nt][r];
      }
    }
}

// ---------------- f32 VALU GEMM for QKV (ex input is f32) ----------------
__global__ __launch_bounds__(256) void gemm48f(const float* __restrict__ X,
                                               const float* __restrict__ Wm,
                                               const float* __restrict__ bias,
                                               float* __restrict__ Out) {
  int b  = blockIdx.z;
  int p0 = blockIdx.x * 128;
  __shared__ __align__(16) float Xs[16][128];
  __shared__ __align__(16) float Ws[16][8][8];
  int tid = threadIdx.x;
  int pg  = tid & 31;
  int og  = tid >> 5;
  float acc[6][4] = {};
  const float* Xb = X + (size_t)b * C_ * HW_;
  for (int k0 = 0; k0 < C_; k0 += 16) {
    {
      int e = tid * 8;
      int kk = e >> 7, px = e & 127;
      float4 a = *(const float4*)(Xb + (size_t)(k0 + kk) * HW_ + p0 + px);
      float4 bv = *(const float4*)(Xb + (size_t)(k0 + kk) * HW_ + p0 + px + 4);
      *(float4*)&Xs[kk][px] = a;
      *(float4*)&Xs[kk][px + 4] = bv;
    }
    #pragma unroll
    for (int i = 0; i < 3; ++i) {
      int e = tid * 3 + i;
      int oo = e >> 4, kk = e & 15;
      Ws[kk][oo / 6][oo % 6] = Wm[(size_t)oo * C_ + k0 + kk];
    }
    __syncthreads();
    #pragma unroll
    for (int kk = 0; kk < 16; ++kk) {
      float4 xv = *(const float4*)&Xs[kk][pg * 4];
      float4 wa = *(const float4*)&Ws[kk][og][0];
      float2 wb = *(const float2*)&Ws[kk][og][4];
      float wv[6] = {wa.x, wa.y, wa.z, wa.w, wb.x, wb.y};
      float xs[4] = {xv.x, xv.y, xv.z, xv.w};
      #pragma unroll
      for (int o = 0; o < 6; ++o)
        #pragma unroll
        for (int pq = 0; pq < 4; ++pq) acc[o][pq] += wv[o] * xs[pq];
    }
    __syncthreads();
  }
  #pragma unroll
  for (int o = 0; o < 6; ++o) {
    int oc = og * 6 + o;
    float bi = bias[oc];
    float4 r;
    r.x = acc[o][0] + bi; r.y = acc[o][1] + bi; r.z = acc[o][2] + bi; r.w = acc[o][3] + bi;
    *(float4*)&Out[((size_t)b * C3_ + oc) * HW_ + p0 + pg * 4] = r;
  }
}

// ---------------- tap-combine: PD/PE rows -> Dx*/Ex* + difference ----------------
__global__ void combine(const float* __restrict__ PD, const float* __restrict__ PE,
                        const float* __restrict__ Db1, const float* __restrict__ Db31,
                        const float* __restrict__ Db51,
                        const float* __restrict__ Eb1, const float* __restrict__ Eb31,
                        const float* __restrict__ Eb51,
                        float* __restrict__ Dx1, float* __restrict__ Dx31, float* __restrict__ Dx51,
                        float* __restrict__ Ex1, float* __restrict__ Ex31, float* __restrict__ Ex51,
                        float* __restrict__ Diff) {
  int idx = blockIdx.x * 256 + threadIdx.x;   // b*16*HW
  int pix = idx & (HW_ - 1);
  int o = (idx >> 14) & 15;
  int b = idx >> 18;
  int y = pix >> 7;
  const float* pd = PD + (size_t)b * O144 * HW_;
  const float* pe = PE + (size_t)b * O144 * HW_;
  float d1 = pd[o * HW_ + pix] + Db1[o];
  float e1 = pe[o * HW_ + pix] + Eb1[o];
  float d31 = Db31[o], e31 = Eb31[o];
  #pragma unroll
  for (int t = 0; t < 3; ++t) {
    int yy = y - 1 + t;
    if (yy >= 0 && yy < H_) {
      int pp = pix + (t - 1) * W_;
      d31 += pd[(16 + t * 16 + o) * HW_ + pp];
      e31 += pe[(16 + t * 16 + o) * HW_ + pp];
    }
  }
  float d51 = Db51[o], e51 = Eb51[o];
  #pragma unroll
  for (int t = 0; t < 5; ++t) {
    int yy = y - 2 + t;
    if (yy >= 0 && yy < H_) {
      int pp = pix + (t - 2) * W_;
      d51 += pd[(64 + t * 16 + o) * HW_ + pp];
      e51 += pe[(64 + t * 16 + o) * HW_ + pp];
    }
  }
  Dx1[idx] = d1;  Ex1[idx] = e1;
  Dx31[idx] = d31; Ex31[idx] = e31;
  Dx51[idx] = d51; Ex51[idx] = e51;
  Diff[idx] = 2.f * d1 + d31 + d51 - 2.f * e1 - e31 - e51;
}

// window loader: 12 floats covering x = xb-4 .. xb+7 with zeros outside [0,128)
__device__ __forceinline__ void loadwin(const float* __restrict__ rowp, int xb, float* buf) {
  int a0 = (xb == 0)   ? 0   : xb - 4;
  int c0 = (xb == 124) ? 124 : xb + 4;
  *(float4*)&buf[0] = *(const float4*)(rowp + a0);
  *(float4*)&buf[4] = *(const float4*)(rowp + xb);
  *(float4*)&buf[8] = *(const float4*)(rowp + c0);
  if (xb == 0)   { buf[0] = buf[1] = buf[2] = buf[3] = 0.f; }
  if (xb == 124) { buf[8] = buf[9] = buf[10] = buf[11] = 0.f; }
}

// ---------------- horizontal 1x3/1x5 convs + BN + relu -> F, 4 px/thread ----------------
__global__ __launch_bounds__(256) void fkern(const float* __restrict__ Dx1, const float* __restrict__ Dx31,
                      const float* __restrict__ Dx51,
                      const float* __restrict__ Ex1, const float* __restrict__ Ex31,
                      const float* __restrict__ Ex51,
                      const float* __restrict__ Dw13, const float* __restrict__ Db13,
                      const float* __restrict__ Dw15, const float* __restrict__ Db15,
                      const float* __restrict__ Ew13, const float* __restrict__ Eb13,
                      const float* __restrict__ Ew15, const float* __restrict__ Eb15,
                      const float* __restrict__ Dg, const float* __restrict__ Dbe,
                      const float* __restrict__ Dm, const float* __restrict__ Dv,
                      const float* __restrict__ Eg, const float* __restrict__ Ebe,
                      const float* __restrict__ Em, const float* __restrict__ Ev,
                      float* __restrict__ F) {
  int idx = blockIdx.x * 256 + threadIdx.x;   // (b, ch48, xq4096)
  int xq = idx & 4095;
  int ch = (idx >> 12) % 48;
  int b  = (idx >> 12) / 48;
  int pix4 = xq * 4;
  int xb = (xq & 31) * 4;
  int rowoff = pix4 - xb;                      // row start within plane
  float dval[4], eval[4];
  if (ch < 16) {
    const float* dp = Dx1 + (((size_t)(b * 16 + ch)) << 14) + pix4;
    const float* ep = Ex1 + (((size_t)(b * 16 + ch)) << 14) + pix4;
    float4 dv = *(const float4*)dp, ev = *(const float4*)ep;
    dval[0]=dv.x; dval[1]=dv.y; dval[2]=dv.z; dval[3]=dv.w;
    eval[0]=ev.x; eval[1]=ev.y; eval[2]=ev.z; eval[3]=ev.w;
  } else if (ch < 32) {
    int o = ch - 16;
    float da[4] = {Db13[o], Db13[o], Db13[o], Db13[o]};
    float ea[4] = {Eb13[o], Eb13[o], Eb13[o], Eb13[o]};
    for (int m = 0; m < 16; ++m) {
      float bd[12], be[12];
      loadwin(Dx31 + (((size_t)(b * 16 + m)) << 14) + rowoff, xb, bd);
      loadwin(Ex31 + (((size_t)(b * 16 + m)) << 14) + rowoff, xb, be);
      #pragma unroll
      for (int t = 0; t < 3; ++t) {
        float wd = Dw13[(o * 16 + m) * 3 + t];
        float we = Ew13[(o * 16 + m) * 3 + t];
        #pragma unroll
        for (int i = 0; i < 4; ++i) {
          da[i] += wd * bd[i + t + 3];
          ea[i] += we * be[i + t + 3];
        }
      }
    }
    #pragma unroll
    for (int i = 0; i < 4; ++i) { dval[i] = da[i]; eval[i] = ea[i]; }
  } else {
    int o = ch - 32;
    float da[4] = {Db15[o], Db15[o], Db15[o], Db15[o]};
    float ea[4] = {Eb15[o], Eb15[o], Eb15[o], Eb15[o]};
    for (int m = 0; m < 16; ++m) {
      float bd[12], be[12];
      loadwin(Dx51 + (((size_t)(b * 16 + m)) << 14) + rowoff, xb, bd);
      loadwin(Ex51 + (((size_t)(b * 16 + m)) << 14) + rowoff, xb, be);
      #pragma unroll
      for (int t = 0; t < 5; ++t) {
        float wd = Dw15[(o * 16 + m) * 5 + t];
        float we = Ew15[(o * 16 + m) * 5 + t];
        #pragma unroll
        for (int i = 0; i < 4; ++i) {
          da[i] += wd * bd[i + t + 2];
          ea[i] += we * be[i + t + 2];
        }
      }
    }
    #pragma unroll
    for (int i = 0; i < 4; ++i) { dval[i] = da[i]; eval[i] = ea[i]; }
  }
  float sD = Dg[ch] * rsqrtf(Dv[ch] + 1e-5f);
  float sE = Eg[ch] * rsqrtf(Ev[ch] + 1e-5f);
  float4 r;
  float* rr = (float*)&r;
  #pragma unroll
  for (int i = 0; i < 4; ++i) {
    float fD = fmaxf((dval[i] - Dm[ch]) * sD + Dbe[ch], 0.f);
    float fE = fmaxf((eval[i] - Em[ch]) * sE + Ebe[ch], 0.f);
    rr[i] = fD - fE;
  }
  *(float4*)&F[(((size_t)(b * 48 + ch)) << 14) + pix4] = r;
}

// ---------------- edge head A: E16[b][o][pix] = relu(pointwise(depthwise(F))) ----------------
__global__ __launch_bounds__(256) void edgeA(const float* __restrict__ F, const float* __restrict__ dww,
                      const float* __restrict__ dwb, const float* __restrict__ pww,
                      const float* __restrict__ pwb, float* __restrict__ E16) {
  int idx = blockIdx.x * 256 + threadIdx.x;   // (b, o16, xq4096)
  int xq = idx & 4095;
  int o  = (idx >> 12) & 15;
  int b  = idx >> 16;
  int pix4 = xq * 4;
  int xb = (xq & 31) * 4;
  int y  = pix4 >> 7;
  int rowoff = pix4 - xb - y * W_;            // = plane-row base offset helper
  const float* Fb = F + (((size_t)b * 48) << 14);
  float e[4] = {pwb[o], pwb[o], pwb[o], pwb[o]};
  for (int g = 0; g < 48; ++g) {
    float dw[4] = {dwb[g], dwb[g], dwb[g], dwb[g]};
    const float* plane = Fb + ((size_t)g << 14);
    #pragma unroll
    for (int dy = 0; dy < 3; ++dy) {
      int yy = y - 1 + dy;
      if (yy < 0 || yy >= H_) continue;
      float buf[12];
      loadwin(plane + yy * W_ + rowoff, xb, buf);
      #pragma unroll
      for (int t = 0; t < 3; ++t) {
        float w = dww[g * 9 + dy * 3 + t];
        #pragma unroll
        for (int i = 0; i < 4; ++i) dw[i] += w * buf[i + t + 3];
      }
    }
    float pw = pww[o * 48 + g];
    #pragma unroll
    for (int i = 0; i < 4; ++i) e[i] += pw * dw[i];
  }
  float4 r;
  r.x = fmaxf(e[0], 0.f); r.y = fmaxf(e[1], 0.f);
  r.z = fmaxf(e[2], 0.f); r.w = fmaxf(e[3], 0.f);
  *(float4*)&E16[(((size_t)(b * 16 + o)) << 14) + pix4] = r;
}

// ---------------- edge head B: mean/max over o + 1x1 conv + sigmoid -> Wedge ----------------
__global__ void edgeB(const float* __restrict__ E16, const float* __restrict__ cw,
                      const float* __restrict__ cb, float* __restrict__ Wedge) {
  int idx = blockIdx.x * 256 + threadIdx.x;   // b*HW
  int pix = idx & (HW_ - 1);
  int b = idx >> 14;
  float sum = 0.f, mx = -INFINITY;
  #pragma unroll
  for (int o = 0; o < 16; ++o) {
    float v = E16[(((size_t)(b * 16 + o)) << 14) + pix];
    sum += v; mx = fmaxf(mx, v);
  }
  float z = cw[0] * (sum * (1.f / 16.f)) + cw[1] * mx + cb[0];
  Wedge[idx] = 1.f / (1.f + expf(-z));
}

// ---------------- attention: weight+gate (Q@K + Q@diff, reshape semantics) ----------------
__global__ void attn_qk(const float* __restrict__ QKV, const float* __restrict__ Diff,
                        float* __restrict__ wsum) {
  int b = blockIdx.y;
  int i = threadIdx.x >> 4, j = threadIdx.x & 15;
  const float* Q  = QKV + (size_t)b * C3_ * HW_;
  const float* Kf = Q + 16 * HW_;
  const float* Df = Diff + (size_t)b * 16 * HW_;
  __shared__ float Qs[16][512];
  __shared__ float KD[512][16];
  float acc = 0.f;
  int p0 = blockIdx.x * 2048;
  for (int c0 = p0; c0 < p0 + 2048; c0 += 512) {
    for (int e = threadIdx.x; e < 16 * 512; e += 256) {
      int r = e >> 9, p = e & 511;
      Qs[r][p] = Q[(r << 14) + c0 + p];
    }
    for (int e = threadIdx.x; e < 512 * 16; e += 256) {
      int f = (c0 << 4) + e;
      KD[e >> 4][e & 15] = Kf[f] + Df[f];
    }
    __syncthreads();
    for (int p = 0; p < 512; ++p) acc += Qs[i][p] * KD[p][j];
    __syncthreads();
  }
  atomicAdd(&wsum[(b << 8) + threadIdx.x], acc);
}

__global__ void softmaxk(const float* __restrict__ wsum, float* __restrict__ wsm) {
  int b = blockIdx.x;
  __shared__ float s[16][16];
  __shared__ float colmx[16], colsum[16];
  int i = threadIdx.x >> 4, j = threadIdx.x & 15;
  s[i][j] = wsum[(b << 8) + threadIdx.x];
  __syncthreads();
  if (threadIdx.x < 16) {
    int jj = threadIdx.x;
    float mx = -INFINITY;
    for (int ii = 0; ii < 16; ++ii) mx = fmaxf(mx, s[ii][jj]);
    float sm = 0.f;
    for (int ii = 0; ii < 16; ++ii) sm += expf(s[ii][jj] - mx);
    colmx[jj] = mx; colsum[jj] = sm;
  }
  __syncthreads();
  wsm[(b << 8) + threadIdx.x] = expf(s[i][j] - colmx[j]) / colsum[j];
}

__global__ void attenx_k(const float* __restrict__ QKV, const float* __restrict__ wsm,
                         const float* __restrict__ Wedge, float* __restrict__ AX) {
  int idx = blockIdx.x * 256 + threadIdx.x;   // b*16*HW
  int pix = idx & (HW_ - 1);
  int m = (idx >> 14) & 15;
  int b = idx >> 18;
  __shared__ float ws[256];
  ws[threadIdx.x] = wsm[(b << 8) + threadIdx.x];
  __syncthreads();
  int q = (m << 10) + (pix >> 4);
  int r = pix & 15;
  const float* V = QKV + (size_t)b * C3_ * HW_ + (size_t)32 * HW_;
  float a = 0.f;
  #pragma unroll
  for (int s = 0; s < 16; ++s) a += ws[(r << 4) + s] * V[(s << 14) + q];
  AX[idx] = a * (1.f + Wedge[(b << 14) + q]);
}

__global__ __launch_bounds__(256) void finalconv(const float* __restrict__ AX,
                                                 const float* __restrict__ rw,
                                                 const float* __restrict__ rb,
                                                 const float* __restrict__ dxin,
                                                 float* __restrict__ out) {
  int blk = blockIdx.x;            // 256 blocks
  int b = blk >> 6;
  int p0 = (blk & 63) << 8;
  __shared__ float ax[16][256];
  for (int e = threadIdx.x; e < 16 * 256; e += 256) {
    int m = e >> 8, p = e & 255;
    ax[m][p] = AX[((size_t)(b * 16 + m) << 14) + p0 + p];
  }
  __syncthreads();
  int p = threadIdx.x;
  for (int oc = 0; oc < 512; ++oc) {
    float a = rb[oc];
    #pragma unroll
    for (int m = 0; m < 16; ++m) a += rw[oc * 16 + m] * ax[m][p];
    size_t oi = ((size_t)(b * C_ + oc) << 14) + p0 + p;
    out[oi] = a + dxin[oi];
  }
}

extern "C" void kernel_launch(void* const* d_in, const int* in_sizes, int n_in,
                              void* d_out, int out_size, void* d_ws, size_t ws_size,
                              hipStream_t stream) {
  (void)in_sizes; (void)n_in; (void)out_size; (void)ws_size;
  const float* ex   = (const float*)d_in[0];
  const float* dx   = (const float*)d_in[1];
  const float* Dw1  = (const float*)d_in[2];
  const float* Db1  = (const float*)d_in[3];
  const float* Dw31 = (const float*)d_in[4];
  const float* Db31 = (const float*)d_in[5];
  const float* Dw13 = (const float*)d_in[6];
  const float* Db13 = (const float*)d_in[7];
  const float* Dw51 = (const float*)d_in[8];
  const float* Db51 = (const float*)d_in[9];
  const float* Dw15 = (const float*)d_in[10];
  const float* Db15 = (const float*)d_in[11];
  const float* Dg   = (const float*)d_in[12];
  const float* Dbe  = (const float*)d_in[13];
  const float* Dm   = (const float*)d_in[14];
  const float* Dv   = (const float*)d_in[15];
  const float* Ew1  = (const float*)d_in[16];
  const float* Eb1  = (const float*)d_in[17];
  const float* Ew31 = (const float*)d_in[18];
  const float* Eb31 = (const float*)d_in[19];
  const float* Ew13 = (const float*)d_in[20];
  const float* Eb13 = (const float*)d_in[21];
  const float* Ew51 = (const float*)d_in[22];
  const float* Eb51 = (const float*)d_in[23];
  const float* Ew15 = (const float*)d_in[24];
  const float* Eb15 = (const float*)d_in[25];
  const float* Eg   = (const float*)d_in[26];
  const float* Ebe  = (const float*)d_in[27];
  const float* Em   = (const float*)d_in[28];
  const float* Ev   = (const float*)d_in[29];
  const float* dww  = (const float*)d_in[30];
  const float* dwb  = (const float*)d_in[31];
  const float* pww  = (const float*)d_in[32];
  const float* pwb  = (const float*)d_in[33];
  const float* qw   = (const float*)d_in[34];
  const float* qb   = (const float*)d_in[35];
  const float* kw   = (const float*)d_in[36];
  const float* kb   = (const float*)d_in[37];
  const float* vw   = (const float*)d_in[38];
  const float* vb   = (const float*)d_in[39];
  const float* rw   = (const float*)d_in[40];
  const float* rb   = (const float*)d_in[41];
  const float* cw   = (const float*)d_in[42];
  const float* cb   = (const float*)d_in[43];

  char* ws = (char*)d_ws;
  bf16_t* DILt = (bf16_t*)(ws + OFF_DILT);
  bf16_t* EROt = (bf16_t*)(ws + OFF_EROT);
  float* PD   = (float*)(ws + OFF_PD);
  float* PE   = (float*)(ws + OFF_PE);
  bf16_t* WDb = (bf16_t*)(ws + OFF_WD);
  bf16_t* WEb = (bf16_t*)(ws + OFF_WE);
  float* WQ   = (float*)(ws + OFF_WQ);
  float* BQ   = (float*)(ws + OFF_BQ);
  float* WSUM = (float*)(ws + OFF_WSUM);
  float* WSM  = (float*)(ws + OFF_WSM);
  float* DX1  = (float*)(ws + OFF_DX1);
  float* DX31 = (float*)(ws + OFF_DX31);
  float* DX51 = (float*)(ws + OFF_DX51);
  float* EX1  = (float*)(ws + OFF_EX1);
  float* EX31 = (float*)(ws + OFF_EX31);
  float* EX51 = (float*)(ws + OFF_EX51);
  float* DIFF = (float*)(ws + OFF_DIFF);
  float* Fb   = (float*)(ws + OFF_F);
  float* QKV  = (float*)(ws + OFF_QKV);
  float* AX   = (float*)(ws + OFF_AX);
  float* WEDG = (float*)(ws + OFF_WEDGE);
  float* E16  = (float*)(ws + OFF_E16);

  prep_weights<<<385, 256, 0, stream>>>(Dw1, Dw31, Dw51, Ew1, Ew31, Ew51,
                                        qw, kw, vw, qb, kb, vb, WDb, WEb, WQ, BQ);
  dilero_t<<<dim3(32, 128, 4), 256, 0, stream>>>(dx, DILt, EROt);
  gemm_mfma<<<dim3(128, 3, 8), 256, 0, stream>>>(WDb, WEb, DILt, EROt, PD, PE);
  combine<<<(N_ * 16 * HW_) / 256, 256, 0, stream>>>(PD, PE, Db1, Db31, Db51, Eb1, Eb31, Eb51,
                                                     DX1, DX31, DX51, EX1, EX31, EX51, DIFF);
  gemm48f<<<dim3(HW_ / 128, 1, N_), 256, 0, stream>>>(ex, WQ, BQ, QKV);
  fkern<<<(N_ * 48 * (HW_ / 4)) / 256, 256, 0, stream>>>(DX1, DX31, DX51, EX1, EX31, EX51,
                                                   Dw13, Db13, Dw15, Db15, Ew13, Eb13, Ew15, Eb15,
                                                   Dg, Dbe, Dm, Dv, Eg, Ebe, Em, Ev, Fb);
  edgeA<<<(N_ * 16 * (HW_ / 4)) / 256, 256, 0, stream>>>(Fb, dww, dwb, pww, pwb, E16);
  edgeB<<<(N_ * HW_) / 256, 256, 0, stream>>>(E16, cw, cb, WEDG);
  hipMemsetAsync(ws + OFF_WSUM, 0, 4096, stream);
  attn_qk<<<dim3(8, N_), 256, 0, stream>>>(QKV, DIFF, WSUM);
  softmaxk<<<N_, 256, 0, stream>>>(WSUM, WSM);
  attenx_k<<<(N_ * 16 * HW_) / 256, 256, 0, stream>>>(QKV, WSM, WEDG, AX);
  finalconv<<<(N_ * HW_) / 256, 256, 0, stream>>>(AX, rw, rb, dx, (float*)d_out);
}

// Round 3
// 802.940 us; speedup vs baseline: 1.4932x; 1.1455x over previous
//
#include <hip/hip_runtime.h>
#include <hip/hip_bf16.h>

typedef __hip_bfloat16 bf16_t;
typedef __attribute__((ext_vector_type(8))) short short8;   // bf16x8 MFMA frag
typedef __attribute__((ext_vector_type(4))) float floatx4;  // f32x4 acc frag

constexpr int N_  = 4;
constexpr int C_  = 512;
constexpr int H_  = 128;
constexpr int W_  = 128;
constexpr int HW_ = H_ * W_;     // 16384
constexpr int O144 = 144;        // stacked D/E GEMM output rows
constexpr int C3_ = 48;

// ---------------- workspace layout (bytes) ----------------
constexpr size_t OFF_DILT = 0;                         // bf16 [4][16384][512] = 67,108,864
constexpr size_t OFF_EROT = 67108864;                  // bf16 67,108,864
constexpr size_t OFF_PD   = 134217728;                 // f32 4*144*16384*4 = 37,748,736
constexpr size_t OFF_PE   = 171966464;                 // f32 37,748,736
constexpr size_t OFF_WD   = 209715200;                 // bf16 144*512*2 = 147,456
constexpr size_t OFF_WE   = 210010112;                 // bf16 147,456
constexpr size_t OFF_WQ   = 210305024;                 // f32 48*512*4 = 98,304
constexpr size_t OFF_BQ   = 210403328;                 // 256
constexpr size_t OFF_WSUM = 210403584;                 // 4096
constexpr size_t OFF_WSM  = 210407680;                 // 4096
// aliased over DILT region (dead after the two MFMA GEMMs):
constexpr size_t OFF_DX1   = 0;
constexpr size_t OFF_DX31  = 4194304;
constexpr size_t OFF_DX51  = 8388608;
constexpr size_t OFF_EX1   = 12582912;
constexpr size_t OFF_EX31  = 16777216;
constexpr size_t OFF_EX51  = 20971520;
constexpr size_t OFF_DIFF  = 25165824;
constexpr size_t OFF_F     = 29360128;                 // 12,582,912
constexpr size_t OFF_QKV   = 41943040;                 // 12,582,912
constexpr size_t OFF_AX    = 54525952;                 // 4,194,304
constexpr size_t OFF_WEDGE = 58720256;                 // 262,144
// aliased over EROT region (dead after GEMMs):
constexpr size_t OFF_DW    = 67108864;                 // f32 4*48*16384*4 = 12,582,912

// ---------------- weight prep: stack striped-conv taps; bf16 for MFMA ----------------
__global__ void prep_weights(const float* __restrict__ Dw1, const float* __restrict__ Dw31,
                             const float* __restrict__ Dw51,
                             const float* __restrict__ Ew1, const float* __restrict__ Ew31,
                             const float* __restrict__ Ew51,
                             const float* __restrict__ qw, const float* __restrict__ kw,
                             const float* __restrict__ vw,
                             const float* __restrict__ qb, const float* __restrict__ kb,
                             const float* __restrict__ vb,
                             bf16_t* __restrict__ WD, bf16_t* __restrict__ WE,
                             float* __restrict__ WQ, float* __restrict__ BQ) {
  int idx = blockIdx.x * 256 + threadIdx.x;
  const int sz = O144 * C_;
  if (idx < sz) {
    int r = idx / C_, c = idx % C_;
    float v;
    if (r < 16)       v = Dw1[r * C_ + c];
    else if (r < 64)  { int t = (r - 16) >> 4, o = (r - 16) & 15; v = Dw31[(o * C_ + c) * 3 + t]; }
    else              { int t = (r - 64) >> 4, o = (r - 64) & 15; v = Dw51[(o * C_ + c) * 5 + t]; }
    WD[idx] = __float2bfloat16(v);
    if (r < 16)       v = Ew1[r * C_ + c];
    else if (r < 64)  { int t = (r - 16) >> 4, o = (r - 16) & 15; v = Ew31[(o * C_ + c) * 3 + t]; }
    else              { int t = (r - 64) >> 4, o = (r - 64) & 15; v = Ew51[(o * C_ + c) * 5 + t]; }
    WE[idx] = __float2bfloat16(v);
  } else if (idx < sz + C3_ * C_) {
    int k = idx - sz;
    int r = k / C_, c = k % C_;
    const float* w = (r < 16) ? qw : (r < 32) ? kw : vw;
    WQ[k] = w[(r & 15) * C_ + c];
  } else if (idx < sz + C3_ * C_ + C3_) {
    int r = idx - sz - C3_ * C_;
    const float* bb = (r < 16) ? qb : (r < 32) ? kb : vb;
    BQ[r] = bb[r & 15];
  }
}

// ---------------- dilate+erode, 8 px/thread, writes TRANSPOSED bf16 [b][pix][c] ----------------
__device__ __forceinline__ void accrow(const float* __restrict__ rowp, int ax, int x0, int dx4,
                                       float* vmax, float* vmin) {
  float buf[16];
  *(float4*)&buf[0]  = *(const float4*)(rowp + ax);
  *(float4*)&buf[4]  = *(const float4*)(rowp + x0);
  *(float4*)&buf[8]  = *(const float4*)(rowp + x0 + 4);
  *(float4*)&buf[12] = *(const float4*)(rowp + dx4);
  #pragma unroll
  for (int j = 0; j < 10; ++j) {
    vmax[j] = fmaxf(vmax[j], buf[j + 3]);
    vmin[j] = fminf(vmin[j], buf[j + 3]);
  }
}

__global__ __launch_bounds__(256) void dilero_t(const float* __restrict__ dxin,
                                                bf16_t* __restrict__ dilT,
                                                bf16_t* __restrict__ eroT) {
  int cT = blockIdx.x, y = blockIdx.y, b = blockIdx.z;
  int t = threadIdx.x;
  int cl = t >> 4;
  int xg = t & 15, x0 = xg * 8;
  int c = cT * 16 + cl;
  const float* p = dxin + ((size_t)(b * C_ + c)) * HW_;
  int ax  = (x0 == 0)   ? 0   : x0 - 4;
  int dx4 = (x0 == 120) ? 124 : x0 + 8;
  float vmax[10], vmin[10];
  #pragma unroll
  for (int j = 0; j < 10; ++j) { vmax[j] = -INFINITY; vmin[j] = INFINITY; }
  if (y > 0)   accrow(p + (y - 1) * W_, ax, x0, dx4, vmax, vmin);
  accrow(p + y * W_, ax, x0, dx4, vmax, vmin);
  if (y < 127) accrow(p + (y + 1) * W_, ax, x0, dx4, vmax, vmin);
  if (xg == 0)  { vmax[0] = -INFINITY; vmin[0] = INFINITY; }
  if (xg == 15) { vmax[9] = -INFINITY; vmin[9] = INFINITY; }
  __shared__ bf16_t ds_d[128][18];
  __shared__ bf16_t ds_e[128][18];
  #pragma unroll
  for (int i = 0; i < 8; ++i) {
    float mx = fmaxf(fmaxf(vmax[i], vmax[i + 1]), vmax[i + 2]);
    float mn = fminf(fminf(vmin[i], vmin[i + 1]), vmin[i + 2]);
    ds_d[x0 + i][cl] = __float2bfloat16(mx);
    ds_e[x0 + i][cl] = __float2bfloat16(mn);
  }
  __syncthreads();
  int j = t & 127;
  const uint* rp = (t >> 7) ? (const uint*)&ds_e[j][0] : (const uint*)&ds_d[j][0];
  uint v0 = rp[0], v1 = rp[1], v2 = rp[2], v3 = rp[3];
  uint v4 = rp[4], v5 = rp[5], v6 = rp[6], v7 = rp[7];
  bf16_t* dst = (t >> 7) ? eroT : dilT;
  size_t base = ((size_t)(b * HW_ + y * W_ + j)) * C_ + cT * 16;
  uint4* op = (uint4*)(dst + base);
  op[0] = make_uint4(v0, v1, v2, v3);
  op[1] = make_uint4(v4, v5, v6, v7);
}

// ---------------- MFMA GEMM: Out[b][144][HW] = W[144][512] @ Xt[b][HW][512]^T ----------------
// grid: (128 pT, 8 = b + 4*map). M=144 per block -> B tile read exactly once from HBM.
__global__ __launch_bounds__(256) void gemm_mfma(const bf16_t* __restrict__ WDb,
                                                 const bf16_t* __restrict__ WEb,
                                                 const bf16_t* __restrict__ DILt,
                                                 const bf16_t* __restrict__ EROt,
                                                 float* __restrict__ PD,
                                                 float* __restrict__ PE) {
  constexpr int LDA = 40;
  constexpr int LDB = 40;
  __shared__ bf16_t As[O144 * LDA];     // 11,520 B
  __shared__ bf16_t Bs[128 * LDB];      // 10,240 B
  int z = blockIdx.y;
  int b = z & 3, map = z >> 2;
  const bf16_t* Wb = map ? WEb : WDb;
  const bf16_t* Xt = map ? EROt : DILt;
  float* Out = map ? PE : PD;
  int p0 = blockIdx.x * 128;
  int tid = threadIdx.x;
  int wave = tid >> 6, lane = tid & 63;
  int quad = lane >> 4, l16 = lane & 15;
  floatx4 acc[9][2] = {};
  const bf16_t* Xb = Xt + ((size_t)b * HW_ + p0) * C_;
  for (int k0 = 0; k0 < C_; k0 += 32) {
    // A tile: 144 x 32 = 576 8-elem chunks
    #pragma unroll
    for (int s = 0; s < 2; ++s) {
      int slot = tid + s * 256;
      int m = slot >> 2, q = slot & 3;
      *(uint4*)(&As[m * LDA + q * 8]) = *(const uint4*)(Wb + (size_t)m * C_ + k0 + q * 8);
    }
    if (tid < 64) {
      int slot = tid + 512;
      int m = slot >> 2, q = slot & 3;
      *(uint4*)(&As[m * LDA + q * 8]) = *(const uint4*)(Wb + (size_t)m * C_ + k0 + q * 8);
    }
    #pragma unroll
    for (int s = 0; s < 2; ++s) {          // B tile: 128 x 32
      int slot = tid + s * 256;
      int pp = slot >> 2, q = slot & 3;
      *(uint4*)(&Bs[pp * LDB + q * 8]) = *(const uint4*)(Xb + (size_t)pp * C_ + k0 + q * 8);
    }
    __syncthreads();
    short8 bfr[2];
    #pragma unroll
    for (int nt = 0; nt < 2; ++nt)
      bfr[nt] = *(const short8*)(&Bs[(wave * 32 + nt * 16 + l16) * LDB + quad * 8]);
    #pragma unroll
    for (int mt = 0; mt < 9; ++mt) {
      short8 afr = *(const short8*)(&As[(mt * 16 + l16) * LDA + quad * 8]);
      #pragma unroll
      for (int nt = 0; nt < 2; ++nt)
        acc[mt][nt] = __builtin_amdgcn_mfma_f32_16x16x32_bf16(afr, bfr[nt], acc[mt][nt], 0, 0, 0);
    }
    __syncthreads();
  }
  #pragma unroll
  for (int mt = 0; mt < 9; ++mt)
    #pragma unroll
    for (int nt = 0; nt < 2; ++nt) {
      int n = p0 + wave * 32 + nt * 16 + l16;
      #pragma unroll
      for (int r = 0; r < 4; ++r) {
        int m = mt * 16 + quad * 4 + r;
        Out[((size_t)b * O144 + m) * HW_ + n] = acc[mt][nt][r];
      }
    }
}

// ---------------- f32 VALU GEMM for QKV (ex input is f32) ----------------
__global__ __launch_bounds__(256) void gemm48f(const float* __restrict__ X,
                                               const float* __restrict__ Wm,
                                               const float* __restrict__ bias,
                                               float* __restrict__ Out) {
  int b  = blockIdx.z;
  int p0 = blockIdx.x * 128;
  __shared__ __align__(16) float Xs[16][128];
  __shared__ __align__(16) float Ws[16][8][8];
  int tid = threadIdx.x;
  int pg  = tid & 31;
  int og  = tid >> 5;
  float acc[6][4] = {};
  const float* Xb = X + (size_t)b * C_ * HW_;
  for (int k0 = 0; k0 < C_; k0 += 16) {
    {
      int e = tid * 8;
      int kk = e >> 7, px = e & 127;
      float4 a = *(const float4*)(Xb + (size_t)(k0 + kk) * HW_ + p0 + px);
      float4 bv = *(const float4*)(Xb + (size_t)(k0 + kk) * HW_ + p0 + px + 4);
      *(float4*)&Xs[kk][px] = a;
      *(float4*)&Xs[kk][px + 4] = bv;
    }
    #pragma unroll
    for (int i = 0; i < 3; ++i) {
      int e = tid * 3 + i;
      int oo = e >> 4, kk = e & 15;
      Ws[kk][oo / 6][oo % 6] = Wm[(size_t)oo * C_ + k0 + kk];
    }
    __syncthreads();
    #pragma unroll
    for (int kk = 0; kk < 16; ++kk) {
      float4 xv = *(const float4*)&Xs[kk][pg * 4];
      float4 wa = *(const float4*)&Ws[kk][og][0];
      float2 wb = *(const float2*)&Ws[kk][og][4];
      float wv[6] = {wa.x, wa.y, wa.z, wa.w, wb.x, wb.y};
      float xs[4] = {xv.x, xv.y, xv.z, xv.w};
      #pragma unroll
      for (int o = 0; o < 6; ++o)
        #pragma unroll
        for (int pq = 0; pq < 4; ++pq) acc[o][pq] += wv[o] * xs[pq];
    }
    __syncthreads();
  }
  #pragma unroll
  for (int o = 0; o < 6; ++o) {
    int oc = og * 6 + o;
    float bi = bias[oc];
    float4 r;
    r.x = acc[o][0] + bi; r.y = acc[o][1] + bi; r.z = acc[o][2] + bi; r.w = acc[o][3] + bi;
    *(float4*)&Out[((size_t)b * C3_ + oc) * HW_ + p0 + pg * 4] = r;
  }
}

// ---------------- tap-combine: PD/PE rows -> Dx*/Ex* + difference ----------------
__global__ void combine(const float* __restrict__ PD, const float* __restrict__ PE,
                        const float* __restrict__ Db1, const float* __restrict__ Db31,
                        const float* __restrict__ Db51,
                        const float* __restrict__ Eb1, const float* __restrict__ Eb31,
                        const float* __restrict__ Eb51,
                        float* __restrict__ Dx1, float* __restrict__ Dx31, float* __restrict__ Dx51,
                        float* __restrict__ Ex1, float* __restrict__ Ex31, float* __restrict__ Ex51,
                        float* __restrict__ Diff) {
  int idx = blockIdx.x * 256 + threadIdx.x;
  int pix = idx & (HW_ - 1);
  int o = (idx >> 14) & 15;
  int b = idx >> 18;
  int y = pix >> 7;
  const float* pd = PD + (size_t)b * O144 * HW_;
  const float* pe = PE + (size_t)b * O144 * HW_;
  float d1 = pd[o * HW_ + pix] + Db1[o];
  float e1 = pe[o * HW_ + pix] + Eb1[o];
  float d31 = Db31[o], e31 = Eb31[o];
  #pragma unroll
  for (int t = 0; t < 3; ++t) {
    int yy = y - 1 + t;
    if (yy >= 0 && yy < H_) {
      int pp = pix + (t - 1) * W_;
      d31 += pd[(16 + t * 16 + o) * HW_ + pp];
      e31 += pe[(16 + t * 16 + o) * HW_ + pp];
    }
  }
  float d51 = Db51[o], e51 = Eb51[o];
  #pragma unroll
  for (int t = 0; t < 5; ++t) {
    int yy = y - 2 + t;
    if (yy >= 0 && yy < H_) {
      int pp = pix + (t - 2) * W_;
      d51 += pd[(64 + t * 16 + o) * HW_ + pp];
      e51 += pe[(64 + t * 16 + o) * HW_ + pp];
    }
  }
  Dx1[idx] = d1;  Ex1[idx] = e1;
  Dx31[idx] = d31; Ex31[idx] = e31;
  Dx51[idx] = d51; Ex51[idx] = e51;
  Diff[idx] = 2.f * d1 + d31 + d51 - 2.f * e1 - e31 - e51;
}

// window loader: 12 floats covering x = xb-4 .. xb+7 with zeros outside [0,128)
__device__ __forceinline__ void loadwin(const float* __restrict__ rowp, int xb, float* buf) {
  int a0 = (xb == 0)   ? 0   : xb - 4;
  int c0 = (xb == 124) ? 124 : xb + 4;
  *(float4*)&buf[0] = *(const float4*)(rowp + a0);
  *(float4*)&buf[4] = *(const float4*)(rowp + xb);
  *(float4*)&buf[8] = *(const float4*)(rowp + c0);
  if (xb == 0)   { buf[0] = buf[1] = buf[2] = buf[3] = 0.f; }
  if (xb == 124) { buf[8] = buf[9] = buf[10] = buf[11] = 0.f; }
}

// ---------------- horizontal 1x3/1x5 convs + BN + relu -> F, 4 px/thread ----------------
__global__ __launch_bounds__(256) void fkern(const float* __restrict__ Dx1, const float* __restrict__ Dx31,
                      const float* __restrict__ Dx51,
                      const float* __restrict__ Ex1, const float* __restrict__ Ex31,
                      const float* __restrict__ Ex51,
                      const float* __restrict__ Dw13, const float* __restrict__ Db13,
                      const float* __restrict__ Dw15, const float* __restrict__ Db15,
                      const float* __restrict__ Ew13, const float* __restrict__ Eb13,
                      const float* __restrict__ Ew15, const float* __restrict__ Eb15,
                      const float* __restrict__ Dg, const float* __restrict__ Dbe,
                      const float* __restrict__ Dm, const float* __restrict__ Dv,
                      const float* __restrict__ Eg, const float* __restrict__ Ebe,
                      const float* __restrict__ Em, const float* __restrict__ Ev,
                      float* __restrict__ F) {
  int idx = blockIdx.x * 256 + threadIdx.x;
  int xq = idx & 4095;
  int ch = (idx >> 12) % 48;
  int b  = (idx >> 12) / 48;
  int pix4 = xq * 4;
  int xb = (xq & 31) * 4;
  int rowoff = pix4 - xb;
  float dval[4], eval[4];
  if (ch < 16) {
    const float* dp = Dx1 + (((size_t)(b * 16 + ch)) << 14) + pix4;
    const float* ep = Ex1 + (((size_t)(b * 16 + ch)) << 14) + pix4;
    float4 dv = *(const float4*)dp, ev = *(const float4*)ep;
    dval[0]=dv.x; dval[1]=dv.y; dval[2]=dv.z; dval[3]=dv.w;
    eval[0]=ev.x; eval[1]=ev.y; eval[2]=ev.z; eval[3]=ev.w;
  } else if (ch < 32) {
    int o = ch - 16;
    float da[4] = {Db13[o], Db13[o], Db13[o], Db13[o]};
    float ea[4] = {Eb13[o], Eb13[o], Eb13[o], Eb13[o]};
    for (int m = 0; m < 16; ++m) {
      float bd[12], be[12];
      loadwin(Dx31 + (((size_t)(b * 16 + m)) << 14) + rowoff, xb, bd);
      loadwin(Ex31 + (((size_t)(b * 16 + m)) << 14) + rowoff, xb, be);
      #pragma unroll
      for (int t = 0; t < 3; ++t) {
        float wd = Dw13[(o * 16 + m) * 3 + t];
        float we = Ew13[(o * 16 + m) * 3 + t];
        #pragma unroll
        for (int i = 0; i < 4; ++i) {
          da[i] += wd * bd[i + t + 3];
          ea[i] += we * be[i + t + 3];
        }
      }
    }
    #pragma unroll
    for (int i = 0; i < 4; ++i) { dval[i] = da[i]; eval[i] = ea[i]; }
  } else {
    int o = ch - 32;
    float da[4] = {Db15[o], Db15[o], Db15[o], Db15[o]};
    float ea[4] = {Eb15[o], Eb15[o], Eb15[o], Eb15[o]};
    for (int m = 0; m < 16; ++m) {
      float bd[12], be[12];
      loadwin(Dx51 + (((size_t)(b * 16 + m)) << 14) + rowoff, xb, bd);
      loadwin(Ex51 + (((size_t)(b * 16 + m)) << 14) + rowoff, xb, be);
      #pragma unroll
      for (int t = 0; t < 5; ++t) {
        float wd = Dw15[(o * 16 + m) * 5 + t];
        float we = Ew15[(o * 16 + m) * 5 + t];
        #pragma unroll
        for (int i = 0; i < 4; ++i) {
          da[i] += wd * bd[i + t + 2];
          ea[i] += we * be[i + t + 2];
        }
      }
    }
    #pragma unroll
    for (int i = 0; i < 4; ++i) { dval[i] = da[i]; eval[i] = ea[i]; }
  }
  float sD = Dg[ch] * rsqrtf(Dv[ch] + 1e-5f);
  float sE = Eg[ch] * rsqrtf(Ev[ch] + 1e-5f);
  float4 r;
  float* rr = (float*)&r;
  #pragma unroll
  for (int i = 0; i < 4; ++i) {
    float fD = fmaxf((dval[i] - Dm[ch]) * sD + Dbe[ch], 0.f);
    float fE = fmaxf((eval[i] - Em[ch]) * sE + Ebe[ch], 0.f);
    rr[i] = fD - fE;
  }
  *(float4*)&F[(((size_t)(b * 48 + ch)) << 14) + pix4] = r;
}

// ---------------- edge depthwise 3x3 (once per channel) ----------------
__global__ __launch_bounds__(256) void edgeDW(const float* __restrict__ F,
                                              const float* __restrict__ dww,
                                              const float* __restrict__ dwb,
                                              float* __restrict__ DW) {
  int idx = blockIdx.x * 256 + threadIdx.x;   // (b, ch48, xq4096)
  int xq = idx & 4095;
  int ch = (idx >> 12) % 48;
  int b  = (idx >> 12) / 48;
  int pix4 = xq * 4;
  int xb = (xq & 31) * 4;
  int y  = pix4 >> 7;
  const float* plane = F + (((size_t)(b * 48 + ch)) << 14);
  float acc[4];
  float bi = dwb[ch];
  acc[0] = bi; acc[1] = bi; acc[2] = bi; acc[3] = bi;
  #pragma unroll
  for (int dy = 0; dy < 3; ++dy) {
    int yy = y - 1 + dy;
    if (yy < 0 || yy >= H_) continue;
    float buf[12];
    loadwin(plane + yy * W_, xb, buf);
    #pragma unroll
    for (int t = 0; t < 3; ++t) {
      float w = dww[ch * 9 + dy * 3 + t];
      #pragma unroll
      for (int i = 0; i < 4; ++i) acc[i] += w * buf[i + t + 3];
    }
  }
  float4 r; r.x = acc[0]; r.y = acc[1]; r.z = acc[2]; r.w = acc[3];
  *(float4*)&DW[(((size_t)(b * 48 + ch)) << 14) + pix4] = r;
}

// ---------------- pointwise 48->16 + relu + mean/max + 1x1 + sigmoid -> Wedge ----------------
__global__ __launch_bounds__(256) void edgeB2(const float* __restrict__ DW,
                                              const float* __restrict__ pww,
                                              const float* __restrict__ pwb,
                                              const float* __restrict__ cw,
                                              const float* __restrict__ cb,
                                              float* __restrict__ Wedge) {
  int idx = blockIdx.x * 256 + threadIdx.x;   // b*HW
  int pix = idx & (HW_ - 1);
  int b = idx >> 14;
  float dwv[48];
  #pragma unroll
  for (int g = 0; g < 48; ++g)
    dwv[g] = DW[(((size_t)(b * 48 + g)) << 14) + pix];
  float sum = 0.f, mx = -INFINITY;
  for (int o = 0; o < 16; ++o) {
    float e = pwb[o];
    #pragma unroll
    for (int g = 0; g < 48; ++g) e += pww[o * 48 + g] * dwv[g];
    e = fmaxf(e, 0.f);
    sum += e; mx = fmaxf(mx, e);
  }
  float z = cw[0] * (sum * (1.f / 16.f)) + cw[1] * mx + cb[0];
  Wedge[idx] = 1.f / (1.f + expf(-z));
}

// ---------------- attention: weight+gate (Q@K + Q@diff, reshape semantics) ----------------
__global__ void attn_qk(const float* __restrict__ QKV, const float* __restrict__ Diff,
                        float* __restrict__ wsum) {
  int b = blockIdx.y;
  int i = threadIdx.x >> 4, j = threadIdx.x & 15;
  const float* Q  = QKV + (size_t)b * C3_ * HW_;
  const float* Kf = Q + 16 * HW_;
  const float* Df = Diff + (size_t)b * 16 * HW_;
  __shared__ float Qs[16][512];
  __shared__ float KD[512][16];
  float acc = 0.f;
  int p0 = blockIdx.x * 2048;
  for (int c0 = p0; c0 < p0 + 2048; c0 += 512) {
    for (int e = threadIdx.x; e < 16 * 512; e += 256) {
      int r = e >> 9, p = e & 511;
      Qs[r][p] = Q[(r << 14) + c0 + p];
    }
    for (int e = threadIdx.x; e < 512 * 16; e += 256) {
      int f = (c0 << 4) + e;
      KD[e >> 4][e & 15] = Kf[f] + Df[f];
    }
    __syncthreads();
    for (int p = 0; p < 512; ++p) acc += Qs[i][p] * KD[p][j];
    __syncthreads();
  }
  atomicAdd(&wsum[(b << 8) + threadIdx.x], acc);
}

__global__ void softmaxk(const float* __restrict__ wsum, float* __restrict__ wsm) {
  int b = blockIdx.x;
  __shared__ float s[16][16];
  __shared__ float colmx[16], colsum[16];
  int i = threadIdx.x >> 4, j = threadIdx.x & 15;
  s[i][j] = wsum[(b << 8) + threadIdx.x];
  __syncthreads();
  if (threadIdx.x < 16) {
    int jj = threadIdx.x;
    float mx = -INFINITY;
    for (int ii = 0; ii < 16; ++ii) mx = fmaxf(mx, s[ii][jj]);
    float sm = 0.f;
    for (int ii = 0; ii < 16; ++ii) sm += expf(s[ii][jj] - mx);
    colmx[jj] = mx; colsum[jj] = sm;
  }
  __syncthreads();
  wsm[(b << 8) + threadIdx.x] = expf(s[i][j] - colmx[j]) / colsum[j];
}

__global__ void attenx_k(const float* __restrict__ QKV, const float* __restrict__ wsm,
                         const float* __restrict__ Wedge, float* __restrict__ AX) {
  int idx = blockIdx.x * 256 + threadIdx.x;
  int pix = idx & (HW_ - 1);
  int m = (idx >> 14) & 15;
  int b = idx >> 18;
  __shared__ float ws[256];
  ws[threadIdx.x] = wsm[(b << 8) + threadIdx.x];
  __syncthreads();
  int q = (m << 10) + (pix >> 4);
  int r = pix & 15;
  const float* V = QKV + (size_t)b * C3_ * HW_ + (size_t)32 * HW_;
  float a = 0.f;
  #pragma unroll
  for (int s = 0; s < 16; ++s) a += ws[(r << 4) + s] * V[(s << 14) + q];
  AX[idx] = a * (1.f + Wedge[(b << 14) + q]);
}

// ---------------- final 16->512 1x1 conv + residual, tiled for occupancy ----------------
__global__ __launch_bounds__(256) void finalconv2(const float* __restrict__ AX,
                                                  const float* __restrict__ rw,
                                                  const float* __restrict__ rb,
                                                  const float* __restrict__ dxin,
                                                  float* __restrict__ out) {
  // grid: (256 px-tiles of 64, 4 b). thread: px4 = (t&15)*4, ocg = t>>4 (32 ocs each)
  int p0 = blockIdx.x * 64;
  int b  = blockIdx.y;
  int t  = threadIdx.x;
  __shared__ float ax[16][64];
  {
    int m = t >> 4, px = (t & 15) * 4;
    *(float4*)&ax[m][px] = *(const float4*)&AX[((size_t)(b * 16 + m) << 14) + p0 + px];
  }
  __syncthreads();
  int px4 = (t & 15) * 4;
  int ocg = t >> 4;
  float4 axr[16];
  #pragma unroll
  for (int m = 0; m < 16; ++m) axr[m] = *(const float4*)&ax[m][px4];
  int oc0 = ocg * 32;
  for (int oc = oc0; oc < oc0 + 32; ++oc) {
    float bi = rb[oc];
    float4 acc; acc.x = bi; acc.y = bi; acc.z = bi; acc.w = bi;
    #pragma unroll
    for (int m = 0; m < 16; ++m) {
      float w = rw[oc * 16 + m];
      acc.x += w * axr[m].x; acc.y += w * axr[m].y;
      acc.z += w * axr[m].z; acc.w += w * axr[m].w;
    }
    size_t oi = ((size_t)(b * C_ + oc) << 14) + p0 + px4;
    float4 dv = *(const float4*)&dxin[oi];
    acc.x += dv.x; acc.y += dv.y; acc.z += dv.z; acc.w += dv.w;
    *(float4*)&out[oi] = acc;
  }
}

extern "C" void kernel_launch(void* const* d_in, const int* in_sizes, int n_in,
                              void* d_out, int out_size, void* d_ws, size_t ws_size,
                              hipStream_t stream) {
  (void)in_sizes; (void)n_in; (void)out_size; (void)ws_size;
  const float* ex   = (const float*)d_in[0];
  const float* dx   = (const float*)d_in[1];
  const float* Dw1  = (const float*)d_in[2];
  const float* Db1  = (const float*)d_in[3];
  const float* Dw31 = (const float*)d_in[4];
  const float* Db31 = (const float*)d_in[5];
  const float* Dw13 = (const float*)d_in[6];
  const float* Db13 = (const float*)d_in[7];
  const float* Dw51 = (const float*)d_in[8];
  const float* Db51 = (const float*)d_in[9];
  const float* Dw15 = (const float*)d_in[10];
  const float* Db15 = (const float*)d_in[11];
  const float* Dg   = (const float*)d_in[12];
  const float* Dbe  = (const float*)d_in[13];
  const float* Dm   = (const float*)d_in[14];
  const float* Dv   = (const float*)d_in[15];
  const float* Ew1  = (const float*)d_in[16];
  const float* Eb1  = (const float*)d_in[17];
  const float* Ew31 = (const float*)d_in[18];
  const float* Eb31 = (const float*)d_in[19];
  const float* Ew13 = (const float*)d_in[20];
  const float* Eb13 = (const float*)d_in[21];
  const float* Ew51 = (const float*)d_in[22];
  const float* Eb51 = (const float*)d_in[23];
  const float* Ew15 = (const float*)d_in[24];
  const float* Eb15 = (const float*)d_in[25];
  const float* Eg   = (const float*)d_in[26];
  const float* Ebe  = (const float*)d_in[27];
  const float* Em   = (const float*)d_in[28];
  const float* Ev   = (const float*)d_in[29];
  const float* dww  = (const float*)d_in[30];
  const float* dwb  = (const float*)d_in[31];
  const float* pww  = (const float*)d_in[32];
  const float* pwb  = (const float*)d_in[33];
  const float* qw   = (const float*)d_in[34];
  const float* qb   = (const float*)d_in[35];
  const float* kw   = (const float*)d_in[36];
  const float* kb   = (const float*)d_in[37];
  const float* vw   = (const float*)d_in[38];
  const float* vb   = (const float*)d_in[39];
  const float* rw   = (const float*)d_in[40];
  const float* rb   = (const float*)d_in[41];
  const float* cw   = (const float*)d_in[42];
  const float* cb   = (const float*)d_in[43];

  char* ws = (char*)d_ws;
  bf16_t* DILt = (bf16_t*)(ws + OFF_DILT);
  bf16_t* EROt = (bf16_t*)(ws + OFF_EROT);
  float* PD   = (float*)(ws + OFF_PD);
  float* PE   = (float*)(ws + OFF_PE);
  bf16_t* WDb = (bf16_t*)(ws + OFF_WD);
  bf16_t* WEb = (bf16_t*)(ws + OFF_WE);
  float* WQ   = (float*)(ws + OFF_WQ);
  float* BQ   = (float*)(ws + OFF_BQ);
  float* WSUM = (float*)(ws + OFF_WSUM);
  float* WSM  = (float*)(ws + OFF_WSM);
  float* DX1  = (float*)(ws + OFF_DX1);
  float* DX31 = (float*)(ws + OFF_DX31);
  float* DX51 = (float*)(ws + OFF_DX51);
  float* EX1  = (float*)(ws + OFF_EX1);
  float* EX31 = (float*)(ws + OFF_EX31);
  float* EX51 = (float*)(ws + OFF_EX51);
  float* DIFF = (float*)(ws + OFF_DIFF);
  float* Fb   = (float*)(ws + OFF_F);
  float* QKV  = (float*)(ws + OFF_QKV);
  float* AX   = (float*)(ws + OFF_AX);
  float* WEDG = (float*)(ws + OFF_WEDGE);
  float* DWb  = (float*)(ws + OFF_DW);

  prep_weights<<<385, 256, 0, stream>>>(Dw1, Dw31, Dw51, Ew1, Ew31, Ew51,
                                        qw, kw, vw, qb, kb, vb, WDb, WEb, WQ, BQ);
  dilero_t<<<dim3(32, 128, 4), 256, 0, stream>>>(dx, DILt, EROt);
  gemm_mfma<<<dim3(128, 8), 256, 0, stream>>>(WDb, WEb, DILt, EROt, PD, PE);
  combine<<<(N_ * 16 * HW_) / 256, 256, 0, stream>>>(PD, PE, Db1, Db31, Db51, Eb1, Eb31, Eb51,
                                                     DX1, DX31, DX51, EX1, EX31, EX51, DIFF);
  gemm48f<<<dim3(HW_ / 128, 1, N_), 256, 0, stream>>>(ex, WQ, BQ, QKV);
  fkern<<<(N_ * 48 * (HW_ / 4)) / 256, 256, 0, stream>>>(DX1, DX31, DX51, EX1, EX31, EX51,
                                                   Dw13, Db13, Dw15, Db15, Ew13, Eb13, Ew15, Eb15,
                                                   Dg, Dbe, Dm, Dv, Eg, Ebe, Em, Ev, Fb);
  edgeDW<<<(N_ * 48 * (HW_ / 4)) / 256, 256, 0, stream>>>(Fb, dww, dwb, DWb);
  edgeB2<<<(N_ * HW_) / 256, 256, 0, stream>>>(DWb, pww, pwb, cw, cb, WEDG);
  hipMemsetAsync(ws + OFF_WSUM, 0, 4096, stream);
  attn_qk<<<dim3(8, N_), 256, 0, stream>>>(QKV, DIFF, WSUM);
  softmaxk<<<N_, 256, 0, stream>>>(WSUM, WSM);
  attenx_k<<<(N_ * 16 * HW_) / 256, 256, 0, stream>>>(QKV, WSM, WEDG, AX);
  finalconv2<<<dim3(256, 4), 256, 0, stream>>>(AX, rw, rb, dx, (float*)d_out);
}